// Round 6
// baseline (194.461 us; speedup 1.0000x reference)
//
#include <hip/hip_runtime.h>
#include <cstdint>
#include <cstddef>

#define NN 8192
#define NE 131072
#define EMB 256

typedef float f32x4 __attribute__((ext_vector_type(4)));
typedef __bf16 bf16x8 __attribute__((ext_vector_type(8)));

__device__ __forceinline__ unsigned short f2bf(float f) {
  unsigned u = __float_as_uint(f);
  u += 0x7fffu + ((u >> 16) & 1u);   // round-to-nearest-even
  return (unsigned short)(u >> 16);
}

__device__ __forceinline__ void gload_lds16(const void* g, void* l) {
  __builtin_amdgcn_global_load_lds(
      (const __attribute__((address_space(1))) unsigned int*)g,
      (__attribute__((address_space(3))) unsigned int*)l, 16, 0, 0);
}

// ---------- node head + bf16 convert + sq norms (must precede adj) ----------
__global__ __launch_bounds__(256) void node_prep_kernel(const float* __restrict__ X,
                                                        const float* __restrict__ w,
                                                        const float* __restrict__ bias,
                                                        float* __restrict__ out,
                                                        unsigned short* __restrict__ Xb,
                                                        float* __restrict__ sq) {
  __shared__ float xs[16 * 260];
  int tid = threadIdx.x;
  int n0  = blockIdx.x * 16;
  int r   = tid >> 4, g = tid & 15;

  float s = 0.f;
  #pragma unroll
  for (int kc = 0; kc < 4; ++kc) {
    float4 v = *(const float4*)(X + (size_t)(n0 + r) * EMB + kc * 64 + g * 4);
    *(float4*)(&xs[r * 260 + kc * 64 + g * 4]) = v;
    s += v.x * v.x + v.y * v.y + v.z * v.z + v.w * v.w;
    ushort4 b;
    b.x = f2bf(v.x); b.y = f2bf(v.y); b.z = f2bf(v.z); b.w = f2bf(v.w);
    *(ushort4*)(Xb + (size_t)(n0 + r) * EMB + kc * 64 + g * 4) = b;
  }
  s += __shfl_xor(s, 1); s += __shfl_xor(s, 2);
  s += __shfl_xor(s, 4); s += __shfl_xor(s, 8);
  if (g == 0) sq[n0 + r] = s;
  __syncthreads();

  int o0 = g * 4;
  float acc[4] = {0.f, 0.f, 0.f, 0.f};
  #pragma unroll 4
  for (int k = 0; k < 256; k += 4) {
    float4 x = *(const float4*)(&xs[r * 260 + k]);
    #pragma unroll
    for (int oo = 0; oo < 4; ++oo) {
      float4 wv = *(const float4*)(w + (size_t)(o0 + oo) * EMB + k);
      acc[oo] = fmaf(x.x, wv.x, fmaf(x.y, wv.y, fmaf(x.z, wv.z, fmaf(x.w, wv.w, acc[oo]))));
    }
  }
  float4 o;
  o.x = acc[0] + bias[o0 + 0];
  o.y = acc[1] + bias[o0 + 1];
  o.z = acc[2] + bias[o0 + 2];
  o.w = acc[3] + bias[o0 + 3];
  *(float4*)(out + (size_t)(n0 + r) * 64 + o0) = o;
}

// ---------- mega: adj 256x256 tiles (1024 blocks) + edge head (256 blocks), 4:1 ----------
// 512 threads. adj: 8 waves (2Mx4N), wave tile 128x64, acc[8][4], BK=64, K=256.
// Staging traffic halves vs 128-tiles (256 MB total). Transposed-square nt stores.
// Per-XCD (b%8) bookkeeping over period-40 block groups keeps 4 A-panels resident
// and advances the B-panel slowly; edge blocks interleave evenly (1 per period/XCD).
__global__ __launch_bounds__(512, 2) void mega_kernel(const unsigned short* __restrict__ Xb,
                                                      const float* __restrict__ sq,
                                                      const float* __restrict__ Wp,
                                                      const float* __restrict__ bp,
                                                      float* __restrict__ adj_out,
                                                      const float* __restrict__ Xe,
                                                      const float* __restrict__ ew,
                                                      const float* __restrict__ eb,
                                                      float* __restrict__ edge_out) {
  __shared__ __align__(16) char smem[65536];
  int tid = threadIdx.x;
  int b   = blockIdx.x;              // 0..1279 ; 1280 = 32 periods * 40
  int x   = b & 7;                   // XCD (blocks round-robin across 8 XCDs)
  int s   = b / 40;                  // period 0..31
  int k   = (b % 40) >> 3;           // slot within period on this XCD, 0..4

  if (((x + 3 * k) % 5) == 4) {
    // ===== edge head: 512 edges/block, [512x256]@[256x16]^T =====
    float* xs = (float*)smem;        // 512*17 floats = 34.8 KB
    int ebid = x * 32 + s;           // 0..255
    int e0 = ebid * 512;
    int lr = tid >> 2, lc = (tid & 3) * 4;   // 4 rows (lr + q*128), 4 cols

    float4 v[4];
    #pragma unroll
    for (int q = 0; q < 4; ++q)
      v[q] = *(const float4*)(Xe + (size_t)(e0 + lr + q * 128) * EMB + lc);

    float acc[16];
    #pragma unroll
    for (int o = 0; o < 16; ++o) acc[o] = 0.f;

    for (int kc = 0; kc < 16; ++kc) {
      __syncthreads();
      #pragma unroll
      for (int q = 0; q < 4; ++q) {
        float* d = &xs[(lr + q * 128) * 17 + lc];
        d[0] = v[q].x; d[1] = v[q].y; d[2] = v[q].z; d[3] = v[q].w;
      }
      __syncthreads();
      if (kc < 15) {
        #pragma unroll
        for (int q = 0; q < 4; ++q)
          v[q] = *(const float4*)(Xe + (size_t)(e0 + lr + q * 128) * EMB + (kc + 1) * 16 + lc);
      }
      const float* wk0 = ew + kc * 16;   // uniform -> s_load
      #pragma unroll
      for (int kk = 0; kk < 16; ++kk) {
        float xv = xs[tid * 17 + kk];
        #pragma unroll
        for (int o = 0; o < 16; ++o)
          acc[o] = fmaf(xv, wk0[(size_t)o * EMB + kk], acc[o]);
      }
    }
    #pragma unroll
    for (int o = 0; o < 16; ++o) acc[o] += eb[o];
    float4* dst = (float4*)(edge_out + (size_t)(e0 + tid) * 16);
    dst[0] = make_float4(acc[0], acc[1], acc[2], acc[3]);
    dst[1] = make_float4(acc[4], acc[5], acc[6], acc[7]);
    dst[2] = make_float4(acc[8], acc[9], acc[10], acc[11]);
    dst[3] = make_float4(acc[12], acc[13], acc[14], acc[15]);
    return;
  }

  // ===== adj 256x256 tile =====
  unsigned short* As = (unsigned short*)smem;        // [256][64] bf16, 32 KB
  unsigned short* Bs = As + 256 * 64;                // [256][64] bf16, 32 KB

  int o = 0;
  #pragma unroll
  for (int kk = 0; kk < 4; ++kk)
    if (kk < k && ((x + 3 * kk) % 5) != 4) ++o;
  int iloc = 4 * s + o;                 // 0..127 per XCD, time-ordered
  int ti = x * 4 + (iloc & 3);          // 4 fixed A-panels per XCD
  int tj = iloc >> 2;                   // B-panel advances every 4 blocks

  int wave = tid >> 6, lane = tid & 63;
  int wm = wave >> 2;                   // 0..1 : wave row (128 rows each)
  int wn = wave & 3;                    // 0..3 : wave col (64 cols each)
  int l15 = lane & 15, lg = lane >> 4;

  f32x4 acc[8][4] = {};

  int r_base = tid >> 3;                // 0..63, + it*64
  int cb     = (tid & 7) << 4;          // byte col within 128B LDS row

  for (int kt = 0; kt < 4; ++kt) {
    #pragma unroll
    for (int it = 0; it < 4; ++it) {
      int r   = it * 64 + r_base;
      int cbs = cb ^ ((r & 7) << 4);    // inverse-swizzled source col
      int col = (kt << 6) + (cbs >> 1);
      gload_lds16(Xb + (size_t)(ti * 256 + r) * EMB + col,
                  (char*)As + it * 8192 + wave * 1024);
      gload_lds16(Xb + (size_t)(tj * 256 + r) * EMB + col,
                  (char*)Bs + it * 8192 + wave * 1024);
    }
    __syncthreads();
    #pragma unroll
    for (int ks = 0; ks < 2; ++ks) {
      bf16x8 af[8], bfr[4];
      #pragma unroll
      for (int m = 0; m < 8; ++m) {
        int rr = wm * 128 + m * 16 + l15;
        int bc = ((ks << 6) + (lg << 4)) ^ ((rr & 7) << 4);
        af[m] = *(const bf16x8*)((const char*)As + rr * 128 + bc);
      }
      #pragma unroll
      for (int n = 0; n < 4; ++n) {
        int rr = wn * 64 + n * 16 + l15;
        int bc = ((ks << 6) + (lg << 4)) ^ ((rr & 7) << 4);
        bfr[n] = *(const bf16x8*)((const char*)Bs + rr * 128 + bc);
      }
      #pragma unroll
      for (int m = 0; m < 8; ++m)
        #pragma unroll
        for (int n = 0; n < 4; ++n)
          acc[m][n] = __builtin_amdgcn_mfma_f32_16x16x32_bf16(af[m], bfr[n], acc[m][n], 0, 0, 0);
    }
    __syncthreads();
  }

  float W0 = Wp[0], b0 = bp[0];
  float w2 = -2.0f * W0;
  int row0 = ti * 256 + wm * 128 + (lg << 2);   // first of 4 consecutive i (per m: +m*16)
  int col0 = tj * 256 + wn * 64 + l15;          // j for this lane (per n: +n*16)
  bool diag = (ti == tj);

  float aiW[32];
  #pragma unroll
  for (int m = 0; m < 8; ++m)
    #pragma unroll
    for (int rg = 0; rg < 4; ++rg)
      aiW[m * 4 + rg] = W0 * sq[row0 + m * 16 + rg];

  #pragma unroll
  for (int n = 0; n < 4; ++n) {
    int j = col0 + n * 16;
    float sjW = fmaf(W0, sq[j], b0);
    #pragma unroll
    for (int m = 0; m < 8; ++m) {
      #pragma unroll
      for (int rg = 0; rg < 4; ++rg) {
        float t = fmaf(w2, acc[m][n][rg], aiW[m * 4 + rg] + sjW);
        acc[m][n][rg] = __builtin_amdgcn_rcpf(1.0f + __expf(-t));
      }
      if (diag) {
        #pragma unroll
        for (int rg = 0; rg < 4; ++rg)
          if (row0 + m * 16 + rg == j) acc[m][n][rg] = 0.0f;
      }
      // adj(i,j)=adj(j,i): store transposed square only — coalesced float4, streaming
      __builtin_nontemporal_store(acc[m][n],
          (f32x4*)(&adj_out[(size_t)j * NN + row0 + m * 16]));
    }
  }
}

extern "C" void kernel_launch(void* const* d_in, const int* in_sizes, int n_in,
                              void* d_out, int out_size, void* d_ws, size_t ws_size,
                              hipStream_t stream) {
  const float* node_emb = (const float*)d_in[0];
  const float* edge_emb = (const float*)d_in[1];
  const float* node_w   = (const float*)d_in[2];
  const float* node_b   = (const float*)d_in[3];
  const float* edge_w   = (const float*)d_in[4];
  const float* edge_b   = (const float*)d_in[5];
  const float* Wp       = (const float*)d_in[6];
  const float* bp       = (const float*)d_in[7];

  float* out      = (float*)d_out;
  float* node_out = out;                        // [8192 x 64]
  float* edge_out = out + (size_t)NN * 64;      // [131072 x 16]
  float* adj_out  = out + (size_t)NN * 64 + (size_t)NE * 16;  // [8192 x 8192]

  unsigned short* Xb = (unsigned short*)d_ws;                       // 4 MiB
  float* sq = (float*)((char*)d_ws + (size_t)NN * EMB * 2);         // 32 KiB

  node_prep_kernel<<<dim3(512), dim3(256), 0, stream>>>(node_emb, node_w, node_b,
                                                        node_out, Xb, sq);
  mega_kernel<<<dim3(1280), dim3(512), 0, stream>>>(Xb, sq, Wp, bp, adj_out,
                                                    edge_emb, edge_w, edge_b, edge_out);
}

// Round 7
// 173.374 us; speedup vs baseline: 1.1216x; 1.1216x over previous
//
#include <hip/hip_runtime.h>
#include <cstdint>
#include <cstddef>

#define NN 8192
#define NE 131072
#define EMB 256

typedef float f32x4 __attribute__((ext_vector_type(4)));
typedef __bf16 bf16x8 __attribute__((ext_vector_type(8)));

__device__ __forceinline__ unsigned short f2bf(float f) {
  unsigned u = __float_as_uint(f);
  u += 0x7fffu + ((u >> 16) & 1u);   // round-to-nearest-even
  return (unsigned short)(u >> 16);
}

__device__ __forceinline__ void gload_lds16(const void* g, void* l) {
  __builtin_amdgcn_global_load_lds(
      (const __attribute__((address_space(1))) unsigned int*)g,
      (__attribute__((address_space(3))) unsigned int*)l, 16, 0, 0);
}

// ---------- node head + bf16 convert + sq norms (must precede adj) ----------
__global__ __launch_bounds__(256) void node_prep_kernel(const float* __restrict__ X,
                                                        const float* __restrict__ w,
                                                        const float* __restrict__ bias,
                                                        float* __restrict__ out,
                                                        unsigned short* __restrict__ Xb,
                                                        float* __restrict__ sq) {
  __shared__ float xs[16 * 260];
  int tid = threadIdx.x;
  int n0  = blockIdx.x * 16;
  int r   = tid >> 4, g = tid & 15;

  float s = 0.f;
  #pragma unroll
  for (int kc = 0; kc < 4; ++kc) {
    float4 v = *(const float4*)(X + (size_t)(n0 + r) * EMB + kc * 64 + g * 4);
    *(float4*)(&xs[r * 260 + kc * 64 + g * 4]) = v;
    s += v.x * v.x + v.y * v.y + v.z * v.z + v.w * v.w;
    ushort4 b;
    b.x = f2bf(v.x); b.y = f2bf(v.y); b.z = f2bf(v.z); b.w = f2bf(v.w);
    *(ushort4*)(Xb + (size_t)(n0 + r) * EMB + kc * 64 + g * 4) = b;
  }
  s += __shfl_xor(s, 1); s += __shfl_xor(s, 2);
  s += __shfl_xor(s, 4); s += __shfl_xor(s, 8);
  if (g == 0) sq[n0 + r] = s;
  __syncthreads();

  int o0 = g * 4;
  float acc[4] = {0.f, 0.f, 0.f, 0.f};
  #pragma unroll 4
  for (int k = 0; k < 256; k += 4) {
    float4 x = *(const float4*)(&xs[r * 260 + k]);
    #pragma unroll
    for (int oo = 0; oo < 4; ++oo) {
      float4 wv = *(const float4*)(w + (size_t)(o0 + oo) * EMB + k);
      acc[oo] = fmaf(x.x, wv.x, fmaf(x.y, wv.y, fmaf(x.z, wv.z, fmaf(x.w, wv.w, acc[oo]))));
    }
  }
  float4 o;
  o.x = acc[0] + bias[o0 + 0];
  o.y = acc[1] + bias[o0 + 1];
  o.z = acc[2] + bias[o0 + 2];
  o.w = acc[3] + bias[o0 + 3];
  *(float4*)(out + (size_t)(n0 + r) * 64 + o0) = o;
}

// ---------- mega: adj 128x128 tiles (4096) + edge head (512), 8:1 interleave ----------
// adj: BK=32, DOUBLE-BUFFERED staging with T3-minimal phase order: issue next K-tile's
// global_load_lds BEFORE computing the current one, so load latency hides under
// ds_read+MFMA and the __syncthreads vmcnt(0) drain at iteration end is cheap.
// LDS rows are 64B (4 slots of 16B); slot swizzle p = lg ^ (row&3) is phase-optimal
// for ds_read_b128 (8 slots x 8 lanes) and applied inversely on the global source.
__global__ __launch_bounds__(256) void mega_kernel(const unsigned short* __restrict__ Xb,
                                                   const float* __restrict__ sq,
                                                   const float* __restrict__ Wp,
                                                   const float* __restrict__ bp,
                                                   float* __restrict__ adj_out,
                                                   const float* __restrict__ Xe,
                                                   const float* __restrict__ ew,
                                                   const float* __restrict__ eb,
                                                   float* __restrict__ edge_out) {
  __shared__ __align__(16) char smem[32768];
  int tid = threadIdx.x;
  int b   = blockIdx.x;           // 0..4607
  int g   = b / 9, rem = b - g * 9;

  if (rem == 8) {
    // ===== edge head: 256 edges/block =====
    float* lds = (float*)smem;    // 256*17 floats = 17.4 KB
    int e0 = g * 256;
    int lr = tid >> 2, lc = (tid & 3) * 4;

    float4 v[4];
    #pragma unroll
    for (int q = 0; q < 4; ++q)
      v[q] = *(const float4*)(Xe + (size_t)(e0 + lr + q * 64) * EMB + lc);

    float acc[16];
    #pragma unroll
    for (int o = 0; o < 16; ++o) acc[o] = 0.f;

    for (int kc = 0; kc < 16; ++kc) {
      __syncthreads();
      #pragma unroll
      for (int q = 0; q < 4; ++q) {
        float* d = &lds[(lr + q * 64) * 17 + lc];
        d[0] = v[q].x; d[1] = v[q].y; d[2] = v[q].z; d[3] = v[q].w;
      }
      __syncthreads();
      if (kc < 15) {
        #pragma unroll
        for (int q = 0; q < 4; ++q)
          v[q] = *(const float4*)(Xe + (size_t)(e0 + lr + q * 64) * EMB + (kc + 1) * 16 + lc);
      }
      const float* wk0 = ew + kc * 16;   // uniform -> s_load
      #pragma unroll
      for (int k = 0; k < 16; ++k) {
        float x = lds[tid * 17 + k];
        #pragma unroll
        for (int o = 0; o < 16; ++o)
          acc[o] = fmaf(x, wk0[(size_t)o * EMB + k], acc[o]);
      }
    }
    #pragma unroll
    for (int o = 0; o < 16; ++o) acc[o] += eb[o];
    float4* dst = (float4*)(edge_out + (size_t)(e0 + tid) * 16);
    dst[0] = make_float4(acc[0], acc[1], acc[2], acc[3]);
    dst[1] = make_float4(acc[4], acc[5], acc[6], acc[7]);
    dst[2] = make_float4(acc[8], acc[9], acc[10], acc[11]);
    dst[3] = make_float4(acc[12], acc[13], acc[14], acc[15]);
    return;
  }

  // ===== adj 128x128 tile, BK=32, double-buffered =====
  // LDS: buf b at smem + b*16384 : A [128][32]bf16 (8 KB) then B (8 KB)
  int adjid = g * 8 + rem;
  int low3  = adjid & 7, q = adjid >> 3;
  int ti = low3 * 8 + (q & 7);                     // 8 fixed A-panels per XCD
  int tj = ((q >> 6) & 7) * 8 + ((q >> 3) & 7);    // B-panel advances slowly

  int wave = tid >> 6, lane = tid & 63;
  int wr = (wave >> 1) * 64;
  int wc = (wave & 1) * 64;
  int l15 = lane & 15, lg = lane >> 4;

  f32x4 acc[4][4] = {};

  // staging geometry: 8 chunks of 1 KB per operand; wave stages chunks 2w, 2w+1
  int srow0 = wave * 32 + (lane >> 2);    // chunk 2w row
  int sp    = lane & 3;                   // physical 16B slot

  const size_t rowA = (size_t)(ti * 128) * EMB;
  const size_t rowB = (size_t)(tj * 128) * EMB;

#define STAGE(BUF, KT)                                                          \
  {                                                                             \
    char* base = smem + (BUF) * 16384;                                          \
    int r0 = srow0, r1 = srow0 + 16;                                            \
    int c0 = (KT) * 32 + ((sp ^ (r0 & 3)) << 3);                                \
    int c1 = (KT) * 32 + ((sp ^ (r1 & 3)) << 3);                                \
    gload_lds16(Xb + rowA + (size_t)r0 * EMB + c0, base + wave * 2048);         \
    gload_lds16(Xb + rowA + (size_t)r1 * EMB + c1, base + wave * 2048 + 1024);  \
    gload_lds16(Xb + rowB + (size_t)r0 * EMB + c0, base + 8192 + wave * 2048);  \
    gload_lds16(Xb + rowB + (size_t)r1 * EMB + c1, base + 8192 + wave * 2048 + 1024); \
  }

  STAGE(0, 0)
  __syncthreads();

  #pragma unroll
  for (int kt = 0; kt < 8; ++kt) {
    if (kt < 7) STAGE((kt + 1) & 1, kt + 1)
    const char* Ab = smem + (kt & 1) * 16384;
    const char* Bb = Ab + 8192;
    bf16x8 af[4], bfr[4];
    #pragma unroll
    for (int m = 0; m < 4; ++m) {
      int rr = wr + m * 16 + l15;
      af[m] = *(const bf16x8*)(Ab + rr * 64 + ((lg ^ (rr & 3)) << 4));
    }
    #pragma unroll
    for (int n = 0; n < 4; ++n) {
      int rr = wc + n * 16 + l15;
      bfr[n] = *(const bf16x8*)(Bb + rr * 64 + ((lg ^ (rr & 3)) << 4));
    }
    #pragma unroll
    for (int m = 0; m < 4; ++m)
      #pragma unroll
      for (int n = 0; n < 4; ++n)
        acc[m][n] = __builtin_amdgcn_mfma_f32_16x16x32_bf16(af[m], bfr[n], acc[m][n], 0, 0, 0);
    __syncthreads();   // drains vmcnt: next-tile loads flew during compute
  }
#undef STAGE

  float W0 = Wp[0], b0 = bp[0];
  float w2 = -2.0f * W0;
  int col0 = tj * 128 + wc + l15;           // j for this lane
  int row0 = ti * 128 + wr + (lg << 2);     // first of 4 consecutive i (per m: +m*16)
  bool diag = (ti == tj);

  float aiW[16];
  #pragma unroll
  for (int m = 0; m < 4; ++m)
    #pragma unroll
    for (int rg = 0; rg < 4; ++rg)
      aiW[m * 4 + rg] = W0 * sq[row0 + m * 16 + rg];

  #pragma unroll
  for (int n = 0; n < 4; ++n) {
    int j = col0 + n * 16;
    float sjW = fmaf(W0, sq[j], b0);
    #pragma unroll
    for (int m = 0; m < 4; ++m) {
      #pragma unroll
      for (int rg = 0; rg < 4; ++rg) {
        float t = fmaf(w2, acc[m][n][rg], aiW[m * 4 + rg] + sjW);
        acc[m][n][rg] = __builtin_amdgcn_rcpf(1.0f + __expf(-t));
      }
      if (diag) {
        #pragma unroll
        for (int rg = 0; rg < 4; ++rg)
          if (row0 + m * 16 + rg == j) acc[m][n][rg] = 0.0f;
      }
      // adj(i,j)=adj(j,i): store transposed square only — coalesced float4, streaming
      __builtin_nontemporal_store(acc[m][n],
          (f32x4*)(&adj_out[(size_t)j * NN + row0 + m * 16]));
    }
  }
}

extern "C" void kernel_launch(void* const* d_in, const int* in_sizes, int n_in,
                              void* d_out, int out_size, void* d_ws, size_t ws_size,
                              hipStream_t stream) {
  const float* node_emb = (const float*)d_in[0];
  const float* edge_emb = (const float*)d_in[1];
  const float* node_w   = (const float*)d_in[2];
  const float* node_b   = (const float*)d_in[3];
  const float* edge_w   = (const float*)d_in[4];
  const float* edge_b   = (const float*)d_in[5];
  const float* Wp       = (const float*)d_in[6];
  const float* bp       = (const float*)d_in[7];

  float* out      = (float*)d_out;
  float* node_out = out;                        // [8192 x 64]
  float* edge_out = out + (size_t)NN * 64;      // [131072 x 16]
  float* adj_out  = out + (size_t)NN * 64 + (size_t)NE * 16;  // [8192 x 8192]

  unsigned short* Xb = (unsigned short*)d_ws;                       // 4 MiB
  float* sq = (float*)((char*)d_ws + (size_t)NN * EMB * 2);         // 32 KiB

  node_prep_kernel<<<dim3(512), dim3(256), 0, stream>>>(node_emb, node_w, node_b,
                                                        node_out, Xb, sq);
  mega_kernel<<<dim3(4608), dim3(256), 0, stream>>>(Xb, sq, Wp, bp, adj_out,
                                                    edge_emb, edge_w, edge_b, edge_out);
}